// Round 10
// baseline (329.506 us; speedup 1.0000x reference)
//
#include <hip/hip_runtime.h>
#include <math.h>

#define BQ 65536
#define NC 512
#define DD 512
#define BM 64
#define BN 256
#define BK 32
#define MARGIN 3e-3f
#define FINF 3.402823466e38f

// A-tile LDS rows padded to 40 shorts (80 B).
#define ASTR 40

typedef short bf16x8 __attribute__((ext_vector_type(8)));
typedef float f32x4 __attribute__((ext_vector_type(4)));

__device__ __forceinline__ unsigned int cvt_pk_bf16(float a, float b) {
    unsigned int r;
    asm("v_cvt_pk_bf16_f32 %0, %1, %2" : "=v"(r) : "v"(a), "v"(b));
    return r;  // low16 = bf16(a) RNE, high16 = bf16(b)
}

// Split 4 fp32 into packed bf16 hi-pairs and lo-pairs (verified since r3).
__device__ __forceinline__ void split4(float4 v, uint2* hi, uint2* lo) {
    unsigned int h0 = cvt_pk_bf16(v.x, v.y);
    unsigned int h1 = cvt_pk_bf16(v.z, v.w);
    float hx = __uint_as_float(h0 << 16);
    float hy = __uint_as_float(h0 & 0xFFFF0000u);
    float hz = __uint_as_float(h1 << 16);
    float hw = __uint_as_float(h1 & 0xFFFF0000u);
    *hi = make_uint2(h0, h1);
    *lo = make_uint2(cvt_pk_bf16(v.x - hx, v.y - hy),
                     cvt_pk_bf16(v.z - hz, v.w - hw));
}

__device__ __forceinline__ float pw128_sq(const float* __restrict__ p) {
    float r[8];
    #pragma unroll
    for (int j = 0; j < 8; ++j) r[j] = 0.0f;
    #pragma unroll
    for (int q = 0; q < 32; ++q) {
        float4 v = *(const float4*)(p + q * 4);
        const int e = (q & 1) << 2;
        r[e + 0] = __fadd_rn(r[e + 0], __fmul_rn(v.x, v.x));
        r[e + 1] = __fadd_rn(r[e + 1], __fmul_rn(v.y, v.y));
        r[e + 2] = __fadd_rn(r[e + 2], __fmul_rn(v.z, v.z));
        r[e + 3] = __fadd_rn(r[e + 3], __fmul_rn(v.w, v.w));
    }
    return __fadd_rn(__fadd_rn(__fadd_rn(r[0], r[1]), __fadd_rn(r[2], r[3])),
                     __fadd_rn(__fadd_rn(r[4], r[5]), __fadd_rn(r[6], r[7])));
}

// Pass 0: csq + codebook bf16 hi/lo split, once for the device. The split
// values are bit-identical to the in-loop cvt8 of rounds 3-9 (same RNE
// cvt_pk + residual), so the GEMM's MFMA inputs are unchanged bit-for-bit.
__global__ __launch_bounds__(256) void prep_kernel(const float* __restrict__ Cb,
                                                   float* __restrict__ csqg,
                                                   unsigned short* __restrict__ Chi,
                                                   unsigned short* __restrict__ Clo) {
    const int code = blockIdx.x * 256 + threadIdx.x;
    const float* p = Cb + (size_t)code * DD;
    float b0 = pw128_sq(p), b1 = pw128_sq(p + 128);
    float b2 = pw128_sq(p + 256), b3 = pw128_sq(p + 384);
    csqg[code] = __fadd_rn(__fadd_rn(b0, b1), __fadd_rn(b2, b3));

    for (int k = 0; k < DD; k += 8) {
        float4 f0 = *(const float4*)(p + k);
        float4 f1 = *(const float4*)(p + k + 4);
        uint2 h0, l0, h1, l1;
        split4(f0, &h0, &l0);
        split4(f1, &h1, &l1);
        *(uint4*)&Chi[(size_t)code * DD + k] = make_uint4(h0.x, h0.y, h1.x, h1.y);
        *(uint4*)&Clo[(size_t)code * DD + k] = make_uint4(l0.x, l0.y, l1.x, l1.y);
    }
}

// Pass 1: r9 skeleton (verified). Changes: B fragments load directly from
// pre-split Chi/Clo (zero VALU on the B path), ring deepened to a full step
// (8 x uint4, distance 4 j-iters; loop-top barrier's vmcnt(0) drain means
// ring data is always resident at consume).
__global__ __launch_bounds__(256, 3) void codebook_kernel(
    const float* __restrict__ Z,
    const unsigned short* __restrict__ Chi, const unsigned short* __restrict__ Clo,
    const float* __restrict__ csqg,
    float* __restrict__ out, int* __restrict__ wslist, int cap) {

    __shared__ __align__(16) unsigned short Ahi[2][BM * ASTR];
    __shared__ __align__(16) unsigned short Alo[2][BM * ASTR];
    __shared__ float csq[NC];
    __shared__ float red_b1[4][BM];
    __shared__ float red_b2[4][BM];
    __shared__ int   red_i1[4][BM];
    __shared__ int   bif[BM];

    const int tid = threadIdx.x;
    const int m0 = blockIdx.x * BM;
    const int l = tid & 63, wid = tid >> 6;
    const int wc0 = wid * 64;            // wave col base within chunk
    const int g = l >> 4, c = l & 15;
    const int ar = tid >> 2, akq = tid & 3;   // A staging: row, k-quad(8 floats)

    if (tid < 128) {
        *(float4*)&csq[tid * 4] = *(const float4*)(csqg + tid * 4);
    }

    float rb1 = FINF, rb2 = FINF; int ri1 = 0;   // running best (tid<64)

    // prologue: load+split tile 0 into buf 0; load va = tile 1; prime B ring
    float4 va0, va1;
    {
        const float* zp = Z + (size_t)(m0 + ar) * DD + akq * 8;
        va0 = *(const float4*)zp;
        va1 = *(const float4*)(zp + 4);
        uint2 h0, l0, h1, l1;
        split4(va0, &h0, &l0);
        split4(va1, &h1, &l1);
        *(uint4*)&Ahi[0][ar * ASTR + akq * 8] = make_uint4(h0.x, h0.y, h1.x, h1.y);
        *(uint4*)&Alo[0][ar * ASTR + akq * 8] = make_uint4(l0.x, l0.y, l1.x, l1.y);
        zp = Z + (size_t)(m0 + ar) * DD + BK + akq * 8;   // tile 1 (kt=32)
        va0 = *(const float4*)zp;
        va1 = *(const float4*)(zp + 4);
    }
    uint4 ring[8];                        // full step-0: (bh, bl) x 4 j-groups
    #pragma unroll
    for (int j = 0; j < 4; ++j) {
        int C = wc0 + j * 16 + c;
        ring[2 * j]     = *(const uint4*)(Chi + (size_t)C * DD + g * 8);
        ring[2 * j + 1] = *(const uint4*)(Clo + (size_t)C * DD + g * 8);
    }
    __syncthreads();

    f32x4 acc[4][4];
    int cur = 0;

    for (int step = 0; step < 32; ++step) {
        const int n0 = (step >> 4) * BN;
        const int t1 = (step < 31) ? step + 1 : 31;      // tile for ring refill
        const int ktn = (t1 & 15) * BK, n0n = (t1 >> 4) * BN;
        const int t2 = (step < 30) ? step + 2 : 31;      // tile for va reload
        const int kt2 = (t2 & 15) * BK;
        const int nxt = cur ^ 1;

        if ((step & 15) == 0) {
            #pragma unroll
            for (int i = 0; i < 4; ++i)
                #pragma unroll
                for (int j = 0; j < 4; ++j) acc[i][j] = (f32x4)0.0f;
        }

        // A fragments from buf[cur] (issue early; bf16 hi/lo direct)
        bf16x8 ah[4], al[4];
        #pragma unroll
        for (int i = 0; i < 4; ++i) {
            int R = i * 16 + c;
            ah[i] = *(bf16x8*)&Ahi[cur][R * ASTR + g * 8];
            al[i] = *(bf16x8*)&Alo[cur][R * ASTR + g * 8];
        }

        // split va (tile step+1) -> buf[nxt]; then reload va = tile step+2
        {
            uint2 h0, l0, h1, l1;
            split4(va0, &h0, &l0);
            split4(va1, &h1, &l1);
            *(uint4*)&Ahi[nxt][ar * ASTR + akq * 8] = make_uint4(h0.x, h0.y, h1.x, h1.y);
            *(uint4*)&Alo[nxt][ar * ASTR + akq * 8] = make_uint4(l0.x, l0.y, l1.x, l1.y);
            const float* zp = Z + (size_t)(m0 + ar) * DD + kt2 + akq * 8;
            va0 = *(const float4*)zp;
            va1 = *(const float4*)(zp + 4);
        }

        // B: consume ring j (this step), refill with next step's j; 48 MFMA
        #pragma unroll
        for (int j = 0; j < 4; ++j) {
            union { uint4 u; bf16x8 v; } BH, BL;
            BH.u = ring[2 * j];
            BL.u = ring[2 * j + 1];
            {
                const int C = n0n + wc0 + j * 16 + c;
                ring[2 * j]     = *(const uint4*)(Chi + (size_t)C * DD + ktn + g * 8);
                ring[2 * j + 1] = *(const uint4*)(Clo + (size_t)C * DD + ktn + g * 8);
            }
            #pragma unroll
            for (int i = 0; i < 4; ++i) {
                acc[i][j] = __builtin_amdgcn_mfma_f32_16x16x32_bf16(ah[i], BH.v, acc[i][j], 0, 0, 0);
                acc[i][j] = __builtin_amdgcn_mfma_f32_16x16x32_bf16(ah[i], BL.v, acc[i][j], 0, 0, 0);
                acc[i][j] = __builtin_amdgcn_mfma_f32_16x16x32_bf16(al[i], BH.v, acc[i][j], 0, 0, 0);
            }
        }

        if ((step & 15) == 15) {
            // chunk epilogue: metric + per-row best/best2
            #pragma unroll
            for (int i = 0; i < 4; ++i) {
                #pragma unroll
                for (int r = 0; r < 4; ++r) {
                    float b1 = FINF, b2 = FINF; int i1 = 0;
                    #pragma unroll
                    for (int j = 0; j < 4; ++j) {
                        int code = n0 + wc0 + j * 16 + c;
                        float m = fmaf(-2.0f, acc[i][j][r], csq[code]);
                        if (m < b1) { b2 = b1; b1 = m; i1 = code; }
                        else b2 = fminf(b2, m);
                    }
                    #pragma unroll
                    for (int s = 1; s < 16; s <<= 1) {
                        float ob1 = __shfl_xor(b1, s);
                        float ob2 = __shfl_xor(b2, s);
                        int oi1 = __shfl_xor(i1, s);
                        if (ob1 < b1 || (ob1 == b1 && oi1 < i1)) {
                            b2 = fminf(b1, ob2); b1 = ob1; i1 = oi1;
                        } else {
                            b2 = fminf(b2, ob1);
                        }
                    }
                    if (c == 0) {
                        int row = i * 16 + g * 4 + r;
                        red_b1[wid][row] = b1;
                        red_b2[wid][row] = b2;
                        red_i1[wid][row] = i1;
                    }
                }
            }
            __syncthreads();
            if (tid < BM) {
                #pragma unroll
                for (int h = 0; h < 4; ++h) {   // ascending code order
                    float nb1 = red_b1[h][tid], nb2 = red_b2[h][tid];
                    int ni = red_i1[h][tid];
                    if (nb1 < rb1) { rb2 = fminf(rb1, nb2); rb1 = nb1; ri1 = ni; }
                    else rb2 = fminf(rb2, nb1);
                }
            }
        }

        __syncthreads();   // buf[nxt] writes visible; buf[cur] reads done (WAR)
        cur = nxt;
    }

    if (tid < BM) {
        bif[tid] = ri1;
        out[(size_t)BQ * NC + m0 + tid] = (float)ri1;
        if (rb2 - rb1 < MARGIN) {
            int slot = atomicAdd(wslist, 1);
            if (slot < cap) wslist[1 + slot] = m0 + tid;
        }
    }
    __syncthreads();

    // one_hot: 64 rows x 512 cols, coalesced float4 stores
    #pragma unroll 4
    for (int t = 0; t < 32; ++t) {
        int f4i = tid + t * 256;
        int r = f4i >> 7, c4 = f4i & 127;
        int tgt = bif[r];
        int base = c4 * 4;
        float4 v;
        v.x = (tgt == base + 0) ? 1.0f : 0.0f;
        v.y = (tgt == base + 1) ? 1.0f : 0.0f;
        v.z = (tgt == base + 2) ? 1.0f : 0.0f;
        v.w = (tgt == base + 3) ? 1.0f : 0.0f;
        *(float4*)(out + (size_t)(m0 + r) * NC + (size_t)base) = v;
    }
}

// Pass 2: fp64-exact argmin for marginal rows (matches numpy-fp64 argmin).
__global__ __launch_bounds__(256) void fixup_kernel(
    const float* __restrict__ Z, const float* __restrict__ Cb,
    float* __restrict__ out, const int* __restrict__ wslist, int cap) {

    __shared__ float zrow[DD];
    __shared__ double md[256];
    __shared__ int mi[256];
    const int tid = threadIdx.x;
    int count = wslist[0];
    if (count > cap) count = cap;

    for (int e = blockIdx.x; e < count; e += gridDim.x) {
        const int row = wslist[1 + e];
        zrow[tid] = Z[(size_t)row * DD + tid];
        zrow[tid + 256] = Z[(size_t)row * DD + 256 + tid];
        __syncthreads();

        double bb = 1e300; int bidx = 0;
        #pragma unroll
        for (int cc = 0; cc < 2; ++cc) {
            const int code = tid * 2 + cc;
            const float* cp = Cb + (size_t)code * DD;
            double dot = 0.0, cs = 0.0;
            for (int k = 0; k < DD; k += 4) {
                float4 c4 = *(const float4*)(cp + k);
                double a0 = (double)zrow[k + 0], c0 = (double)c4.x;
                double a1 = (double)zrow[k + 1], c1 = (double)c4.y;
                double a2 = (double)zrow[k + 2], c2 = (double)c4.z;
                double a3 = (double)zrow[k + 3], c3 = (double)c4.w;
                dot = fma(a0, c0, dot); cs = fma(c0, c0, cs);
                dot = fma(a1, c1, dot); cs = fma(c1, c1, cs);
                dot = fma(a2, c2, dot); cs = fma(c2, c2, cs);
                dot = fma(a3, c3, dot); cs = fma(c3, c3, cs);
            }
            double m = cs - 2.0 * dot;
            if (m < bb || (m == bb && code < bidx)) { bb = m; bidx = code; }
        }
        md[tid] = bb; mi[tid] = bidx;
        __syncthreads();
        for (int s = 128; s > 0; s >>= 1) {
            if (tid < s) {
                if (md[tid + s] < md[tid] ||
                    (md[tid + s] == md[tid] && mi[tid + s] < mi[tid])) {
                    md[tid] = md[tid + s]; mi[tid] = mi[tid + s];
                }
            }
            __syncthreads();
        }
        const int imin = mi[0];
        out[(size_t)row * NC + tid] = (tid == imin) ? 1.0f : 0.0f;
        out[(size_t)row * NC + 256 + tid] = (tid + 256 == imin) ? 1.0f : 0.0f;
        if (tid == 0) out[(size_t)BQ * NC + row] = (float)imin;
        __syncthreads();
    }
}

extern "C" void kernel_launch(void* const* d_in, const int* in_sizes, int n_in,
                              void* d_out, int out_size, void* d_ws, size_t ws_size,
                              hipStream_t stream) {
    const float* Z = (const float*)d_in[0];
    const float* Cb = (const float*)d_in[1];
    float* out = (float*)d_out;

    // ws layout: [wslist: 64KB][csqg: 2KB][Chi: 512KB][Clo: 512KB]
    char* wsb = (char*)d_ws;
    int* wslist = (int*)wsb;
    float* csqg = (float*)(wsb + 65536);
    unsigned short* Chi = (unsigned short*)(wsb + 65536 + 2048);
    unsigned short* Clo = (unsigned short*)(wsb + 65536 + 2048 + NC * DD * 2);
    int cap = 16383;

    prep_kernel<<<dim3(2), dim3(256), 0, stream>>>(Cb, csqg, Chi, Clo);
    hipMemsetAsync(wsb, 0, 4, stream);  // zero worklist counter
    codebook_kernel<<<dim3(BQ / BM), dim3(256), 0, stream>>>(Z, Chi, Clo, csqg, out, wslist, cap);
    fixup_kernel<<<dim3(512), dim3(256), 0, stream>>>(Z, Cb, out, wslist, cap);
}

// Round 11
// 329.327 us; speedup vs baseline: 1.0005x; 1.0005x over previous
//
#include <hip/hip_runtime.h>
#include <math.h>

#define BQ 65536
#define NC 512
#define DD 512
#define BM 64
#define BN 256
#define BK 32
#define MARGIN 3e-3f
#define FINF 3.402823466e38f

// A-tile LDS rows padded to 40 shorts (80 B).
#define ASTR 40

typedef short bf16x8 __attribute__((ext_vector_type(8)));
typedef float f32x4 __attribute__((ext_vector_type(4)));

// Barrier that drains ONLY LDS ops (not VMEM): global prefetches in registers
// stay in flight across it; their consumers are protected by compiler-inserted
// vmcnt waits. sched_barrier fences stop cross-barrier code motion (rule #18).
__device__ __forceinline__ void block_sync_lds() {
    __builtin_amdgcn_sched_barrier(0);
    asm volatile("s_waitcnt lgkmcnt(0)" ::: "memory");
    __builtin_amdgcn_s_barrier();
    __builtin_amdgcn_sched_barrier(0);
}

__device__ __forceinline__ unsigned int cvt_pk_bf16(float a, float b) {
    unsigned int r;
    asm("v_cvt_pk_bf16_f32 %0, %1, %2" : "=v"(r) : "v"(a), "v"(b));
    return r;  // low16 = bf16(a) RNE, high16 = bf16(b)
}

// Split 4 fp32 into packed bf16 hi-pairs and lo-pairs (verified since r3).
__device__ __forceinline__ void split4(float4 v, uint2* hi, uint2* lo) {
    unsigned int h0 = cvt_pk_bf16(v.x, v.y);
    unsigned int h1 = cvt_pk_bf16(v.z, v.w);
    float hx = __uint_as_float(h0 << 16);
    float hy = __uint_as_float(h0 & 0xFFFF0000u);
    float hz = __uint_as_float(h1 << 16);
    float hw = __uint_as_float(h1 & 0xFFFF0000u);
    *hi = make_uint2(h0, h1);
    *lo = make_uint2(cvt_pk_bf16(v.x - hx, v.y - hy),
                     cvt_pk_bf16(v.z - hz, v.w - hw));
}

__device__ __forceinline__ float pw128_sq(const float* __restrict__ p) {
    float r[8];
    #pragma unroll
    for (int j = 0; j < 8; ++j) r[j] = 0.0f;
    #pragma unroll
    for (int q = 0; q < 32; ++q) {
        float4 v = *(const float4*)(p + q * 4);
        const int e = (q & 1) << 2;
        r[e + 0] = __fadd_rn(r[e + 0], __fmul_rn(v.x, v.x));
        r[e + 1] = __fadd_rn(r[e + 1], __fmul_rn(v.y, v.y));
        r[e + 2] = __fadd_rn(r[e + 2], __fmul_rn(v.z, v.z));
        r[e + 3] = __fadd_rn(r[e + 3], __fmul_rn(v.w, v.w));
    }
    return __fadd_rn(__fadd_rn(__fadd_rn(r[0], r[1]), __fadd_rn(r[2], r[3])),
                     __fadd_rn(__fadd_rn(r[4], r[5]), __fadd_rn(r[6], r[7])));
}

// Pass 0: csq + codebook bf16 hi/lo split, once for the device (bit-identical
// values to the in-loop cvt8 of rounds 3-9).
__global__ __launch_bounds__(256) void prep_kernel(const float* __restrict__ Cb,
                                                   float* __restrict__ csqg,
                                                   unsigned short* __restrict__ Chi,
                                                   unsigned short* __restrict__ Clo) {
    const int code = blockIdx.x * 256 + threadIdx.x;
    const float* p = Cb + (size_t)code * DD;
    float b0 = pw128_sq(p), b1 = pw128_sq(p + 128);
    float b2 = pw128_sq(p + 256), b3 = pw128_sq(p + 384);
    csqg[code] = __fadd_rn(__fadd_rn(b0, b1), __fadd_rn(b2, b3));

    for (int k = 0; k < DD; k += 8) {
        float4 f0 = *(const float4*)(p + k);
        float4 f1 = *(const float4*)(p + k + 4);
        uint2 h0, l0, h1, l1;
        split4(f0, &h0, &l0);
        split4(f1, &h1, &l1);
        *(uint4*)&Chi[(size_t)code * DD + k] = make_uint4(h0.x, h0.y, h1.x, h1.y);
        *(uint4*)&Clo[(size_t)code * DD + k] = make_uint4(l0.x, l0.y, l1.x, l1.y);
    }
}

// Pass 1: r10 skeleton (verified), ONE change: main-loop barrier no longer
// drains vmcnt (block_sync_lds) -> the va (step+2) and B-ring (step+1)
// register prefetches stay in flight across barriers, giving them a full
// step (~5K cyc) of latency cover instead of sub-step.
__global__ __launch_bounds__(256, 3) void codebook_kernel(
    const float* __restrict__ Z,
    const unsigned short* __restrict__ Chi, const unsigned short* __restrict__ Clo,
    const float* __restrict__ csqg,
    float* __restrict__ out, int* __restrict__ wslist, int cap) {

    __shared__ __align__(16) unsigned short Ahi[2][BM * ASTR];
    __shared__ __align__(16) unsigned short Alo[2][BM * ASTR];
    __shared__ float csq[NC];
    __shared__ float red_b1[4][BM];
    __shared__ float red_b2[4][BM];
    __shared__ int   red_i1[4][BM];
    __shared__ int   bif[BM];

    const int tid = threadIdx.x;
    const int m0 = blockIdx.x * BM;
    const int l = tid & 63, wid = tid >> 6;
    const int wc0 = wid * 64;            // wave col base within chunk
    const int g = l >> 4, c = l & 15;
    const int ar = tid >> 2, akq = tid & 3;   // A staging: row, k-quad(8 floats)

    if (tid < 128) {
        *(float4*)&csq[tid * 4] = *(const float4*)(csqg + tid * 4);
    }

    float rb1 = FINF, rb2 = FINF; int ri1 = 0;   // running best (tid<64)

    // prologue: load+split tile 0 into buf 0; load va = tile 1; prime B ring
    float4 va0, va1;
    {
        const float* zp = Z + (size_t)(m0 + ar) * DD + akq * 8;
        va0 = *(const float4*)zp;
        va1 = *(const float4*)(zp + 4);
        uint2 h0, l0, h1, l1;
        split4(va0, &h0, &l0);
        split4(va1, &h1, &l1);
        *(uint4*)&Ahi[0][ar * ASTR + akq * 8] = make_uint4(h0.x, h0.y, h1.x, h1.y);
        *(uint4*)&Alo[0][ar * ASTR + akq * 8] = make_uint4(l0.x, l0.y, l1.x, l1.y);
        zp = Z + (size_t)(m0 + ar) * DD + BK + akq * 8;   // tile 1 (kt=32)
        va0 = *(const float4*)zp;
        va1 = *(const float4*)(zp + 4);
    }
    uint4 ring[8];                        // full step-0: (bh, bl) x 4 j-groups
    #pragma unroll
    for (int j = 0; j < 4; ++j) {
        int C = wc0 + j * 16 + c;
        ring[2 * j]     = *(const uint4*)(Chi + (size_t)C * DD + g * 8);
        ring[2 * j + 1] = *(const uint4*)(Clo + (size_t)C * DD + g * 8);
    }
    __syncthreads();

    f32x4 acc[4][4];
    int cur = 0;

    for (int step = 0; step < 32; ++step) {
        const int n0 = (step >> 4) * BN;
        const int t1 = (step < 31) ? step + 1 : 31;      // tile for ring refill
        const int ktn = (t1 & 15) * BK, n0n = (t1 >> 4) * BN;
        const int t2 = (step < 30) ? step + 2 : 31;      // tile for va reload
        const int kt2 = (t2 & 15) * BK;
        const int nxt = cur ^ 1;

        if ((step & 15) == 0) {
            #pragma unroll
            for (int i = 0; i < 4; ++i)
                #pragma unroll
                for (int j = 0; j < 4; ++j) acc[i][j] = (f32x4)0.0f;
        }

        // A fragments from buf[cur] (issue early; bf16 hi/lo direct)
        bf16x8 ah[4], al[4];
        #pragma unroll
        for (int i = 0; i < 4; ++i) {
            int R = i * 16 + c;
            ah[i] = *(bf16x8*)&Ahi[cur][R * ASTR + g * 8];
            al[i] = *(bf16x8*)&Alo[cur][R * ASTR + g * 8];
        }

        // split va (tile step+1) -> buf[nxt]; then reload va = tile step+2
        {
            uint2 h0, l0, h1, l1;
            split4(va0, &h0, &l0);
            split4(va1, &h1, &l1);
            *(uint4*)&Ahi[nxt][ar * ASTR + akq * 8] = make_uint4(h0.x, h0.y, h1.x, h1.y);
            *(uint4*)&Alo[nxt][ar * ASTR + akq * 8] = make_uint4(l0.x, l0.y, l1.x, l1.y);
            const float* zp = Z + (size_t)(m0 + ar) * DD + kt2 + akq * 8;
            va0 = *(const float4*)zp;
            va1 = *(const float4*)(zp + 4);
        }

        // B: consume ring j (this step), refill with next step's j; 48 MFMA
        #pragma unroll
        for (int j = 0; j < 4; ++j) {
            union { uint4 u; bf16x8 v; } BH, BL;
            BH.u = ring[2 * j];
            BL.u = ring[2 * j + 1];
            {
                const int C = n0n + wc0 + j * 16 + c;
                ring[2 * j]     = *(const uint4*)(Chi + (size_t)C * DD + ktn + g * 8);
                ring[2 * j + 1] = *(const uint4*)(Clo + (size_t)C * DD + ktn + g * 8);
            }
            #pragma unroll
            for (int i = 0; i < 4; ++i) {
                acc[i][j] = __builtin_amdgcn_mfma_f32_16x16x32_bf16(ah[i], BH.v, acc[i][j], 0, 0, 0);
                acc[i][j] = __builtin_amdgcn_mfma_f32_16x16x32_bf16(ah[i], BL.v, acc[i][j], 0, 0, 0);
                acc[i][j] = __builtin_amdgcn_mfma_f32_16x16x32_bf16(al[i], BH.v, acc[i][j], 0, 0, 0);
            }
        }

        if ((step & 15) == 15) {
            // chunk epilogue: metric + per-row best/best2
            #pragma unroll
            for (int i = 0; i < 4; ++i) {
                #pragma unroll
                for (int r = 0; r < 4; ++r) {
                    float b1 = FINF, b2 = FINF; int i1 = 0;
                    #pragma unroll
                    for (int j = 0; j < 4; ++j) {
                        int code = n0 + wc0 + j * 16 + c;
                        float m = fmaf(-2.0f, acc[i][j][r], csq[code]);
                        if (m < b1) { b2 = b1; b1 = m; i1 = code; }
                        else b2 = fminf(b2, m);
                    }
                    #pragma unroll
                    for (int s = 1; s < 16; s <<= 1) {
                        float ob1 = __shfl_xor(b1, s);
                        float ob2 = __shfl_xor(b2, s);
                        int oi1 = __shfl_xor(i1, s);
                        if (ob1 < b1 || (ob1 == b1 && oi1 < i1)) {
                            b2 = fminf(b1, ob2); b1 = ob1; i1 = oi1;
                        } else {
                            b2 = fminf(b2, ob1);
                        }
                    }
                    if (c == 0) {
                        int row = i * 16 + g * 4 + r;
                        red_b1[wid][row] = b1;
                        red_b2[wid][row] = b2;
                        red_i1[wid][row] = i1;
                    }
                }
            }
            __syncthreads();
            if (tid < BM) {
                #pragma unroll
                for (int h = 0; h < 4; ++h) {   // ascending code order
                    float nb1 = red_b1[h][tid], nb2 = red_b2[h][tid];
                    int ni = red_i1[h][tid];
                    if (nb1 < rb1) { rb2 = fminf(rb1, nb2); rb1 = nb1; ri1 = ni; }
                    else rb2 = fminf(rb2, nb1);
                }
            }
        }

        block_sync_lds();  // LDS-only drain: buf[nxt] visible, buf[cur] WAR safe
        cur = nxt;
    }

    if (tid < BM) {
        bif[tid] = ri1;
        out[(size_t)BQ * NC + m0 + tid] = (float)ri1;
        if (rb2 - rb1 < MARGIN) {
            int slot = atomicAdd(wslist, 1);
            if (slot < cap) wslist[1 + slot] = m0 + tid;
        }
    }
    __syncthreads();

    // one_hot: 64 rows x 512 cols, coalesced float4 stores
    #pragma unroll 4
    for (int t = 0; t < 32; ++t) {
        int f4i = tid + t * 256;
        int r = f4i >> 7, c4 = f4i & 127;
        int tgt = bif[r];
        int base = c4 * 4;
        float4 v;
        v.x = (tgt == base + 0) ? 1.0f : 0.0f;
        v.y = (tgt == base + 1) ? 1.0f : 0.0f;
        v.z = (tgt == base + 2) ? 1.0f : 0.0f;
        v.w = (tgt == base + 3) ? 1.0f : 0.0f;
        *(float4*)(out + (size_t)(m0 + r) * NC + (size_t)base) = v;
    }
}

// Pass 2: fp64-exact argmin for marginal rows (matches numpy-fp64 argmin).
__global__ __launch_bounds__(256) void fixup_kernel(
    const float* __restrict__ Z, const float* __restrict__ Cb,
    float* __restrict__ out, const int* __restrict__ wslist, int cap) {

    __shared__ float zrow[DD];
    __shared__ double md[256];
    __shared__ int mi[256];
    const int tid = threadIdx.x;
    int count = wslist[0];
    if (count > cap) count = cap;

    for (int e = blockIdx.x; e < count; e += gridDim.x) {
        const int row = wslist[1 + e];
        zrow[tid] = Z[(size_t)row * DD + tid];
        zrow[tid + 256] = Z[(size_t)row * DD + 256 + tid];
        __syncthreads();

        double bb = 1e300; int bidx = 0;
        #pragma unroll
        for (int cc = 0; cc < 2; ++cc) {
            const int code = tid * 2 + cc;
            const float* cp = Cb + (size_t)code * DD;
            double dot = 0.0, cs = 0.0;
            for (int k = 0; k < DD; k += 4) {
                float4 c4 = *(const float4*)(cp + k);
                double a0 = (double)zrow[k + 0], c0 = (double)c4.x;
                double a1 = (double)zrow[k + 1], c1 = (double)c4.y;
                double a2 = (double)zrow[k + 2], c2 = (double)c4.z;
                double a3 = (double)zrow[k + 3], c3 = (double)c4.w;
                dot = fma(a0, c0, dot); cs = fma(c0, c0, cs);
                dot = fma(a1, c1, dot); cs = fma(c1, c1, cs);
                dot = fma(a2, c2, dot); cs = fma(c2, c2, cs);
                dot = fma(a3, c3, dot); cs = fma(c3, c3, cs);
            }
            double m = cs - 2.0 * dot;
            if (m < bb || (m == bb && code < bidx)) { bb = m; bidx = code; }
        }
        md[tid] = bb; mi[tid] = bidx;
        __syncthreads();
        for (int s = 128; s > 0; s >>= 1) {
            if (tid < s) {
                if (md[tid + s] < md[tid] ||
                    (md[tid + s] == md[tid] && mi[tid + s] < mi[tid])) {
                    md[tid] = md[tid + s]; mi[tid] = mi[tid + s];
                }
            }
            __syncthreads();
        }
        const int imin = mi[0];
        out[(size_t)row * NC + tid] = (tid == imin) ? 1.0f : 0.0f;
        out[(size_t)row * NC + 256 + tid] = (tid + 256 == imin) ? 1.0f : 0.0f;
        if (tid == 0) out[(size_t)BQ * NC + row] = (float)imin;
        __syncthreads();
    }
}

extern "C" void kernel_launch(void* const* d_in, const int* in_sizes, int n_in,
                              void* d_out, int out_size, void* d_ws, size_t ws_size,
                              hipStream_t stream) {
    const float* Z = (const float*)d_in[0];
    const float* Cb = (const float*)d_in[1];
    float* out = (float*)d_out;

    // ws layout: [wslist: 64KB][csqg: 2KB][Chi: 512KB][Clo: 512KB]
    char* wsb = (char*)d_ws;
    int* wslist = (int*)wsb;
    float* csqg = (float*)(wsb + 65536);
    unsigned short* Chi = (unsigned short*)(wsb + 65536 + 2048);
    unsigned short* Clo = (unsigned short*)(wsb + 65536 + 2048 + NC * DD * 2);
    int cap = 16383;

    prep_kernel<<<dim3(2), dim3(256), 0, stream>>>(Cb, csqg, Chi, Clo);
    hipMemsetAsync(wsb, 0, 4, stream);  // zero worklist counter
    codebook_kernel<<<dim3(BQ / BM), dim3(256), 0, stream>>>(Z, Chi, Clo, csqg, out, wslist, cap);
    fixup_kernel<<<dim3(512), dim3(256), 0, stream>>>(Z, Cb, out, wslist, cap);
}